// Round 11
// baseline (307.029 us; speedup 1.0000x reference)
//
#include <hip/hip_runtime.h>

#define HH 512
#define WW 512
#define NB 4

typedef float v2f __attribute__((ext_vector_type(2)));

// Packed stage2 weights live in the unused tail of d_out (combine_kernel
// rewrites the ENTIRE 4MB output buffer afterwards -> safe scratch, r6-proven).
// Wg3[c][t][kx][d] : d=0..7 output-row offset, t=0..29 staged row,
// value = Wg[c][t-d][kx] if 0<=t-d<23 else 0.  16*30*23*8 = 88320 floats.
#define WG3_ELEMS 88320

__global__ __launch_bounds__(256) void prep_kernel(
    const float* __restrict__ Wg, float* __restrict__ Wg3)
{
    const int e = blockIdx.x * 256 + threadIdx.x;
    if (e >= WG3_ELEMS) return;
    const int d  = e & 7;
    const int r  = e >> 3;
    const int kx = r % 23;
    const int r2 = r / 23;
    const int t  = r2 % 30;
    const int c  = r2 / 30;
    const int ky = t - d;
    Wg3[e] = (ky >= 0 && ky < 23) ? Wg[c * 529 + ky * 23 + kx] : 0.f;
}

// ---------------- Stage 1: 11x11 convs (1->8, pos & neg) + spike/WTA logic ----------------
// Round-19 version (fused pos+neg, 4 px/thread) — unchanged this round.
#define K1 11
#define PAD1 5
#define T1X 32
#define T1Y 32
#define IN1 42        // 32 + 10 halo
#define S1B 44        // LDS row stride (even -> b64-aligned float2 reads)

__global__ __launch_bounds__(256, 4) void stage1_kernel(
    const float* __restrict__ inp, const float* __restrict__ Wb,
    unsigned char* __restrict__ border)
{
    __shared__ __align__(16) float s0[IN1 * S1B];
    __shared__ __align__(16) float s1[IN1 * S1B];

    const int b   = blockIdx.z;
    const int tx0 = blockIdx.x * T1X;
    const int ty0 = blockIdx.y * T1Y;
    const float* in0 = inp + ((size_t)b * 2 + 0) * (HH * WW);
    const float* in1 = inp + ((size_t)b * 2 + 1) * (HH * WW);

    for (int i = threadIdx.x; i < IN1 * IN1; i += 256) {
        int iy = i / IN1, ix = i - iy * IN1;
        int gy = ty0 + iy - PAD1, gx = tx0 + ix - PAD1;
        bool ok = (gy >= 0) & (gy < HH) & (gx >= 0) & (gx < WW);
        int idx = gy * WW + gx;
        s0[iy * S1B + ix] = ok ? in0[idx] : 0.f;
        s1[iy * S1B + ix] = ok ? in1[idx] : 0.f;
    }
    __syncthreads();

    const int lx  = threadIdx.x & 7;    // 8 x-groups of 4 px -> 32 wide
    const int ly  = threadIdx.x >> 3;   // 32 rows
    const int px0 = lx * 4;
    const int py  = ly;

    float accP[8][4], accN[8][4];
    #pragma unroll
    for (int c = 0; c < 8; c++)
        #pragma unroll
        for (int p = 0; p < 4; p++) { accP[c][p] = 0.f; accN[c][p] = 0.f; }

    #pragma unroll 1
    for (int ky = 0; ky < K1; ky++) {
        float a0[14], a1[14];
        const float2* r0 = (const float2*)&s0[(py + ky) * S1B + px0];
        const float2* r1 = (const float2*)&s1[(py + ky) * S1B + px0];
        #pragma unroll
        for (int r = 0; r < 7; r++) {
            *(float2*)&a0[2 * r] = r0[r];
            *(float2*)&a1[2 * r] = r1[r];
        }
        #pragma unroll
        for (int c = 0; c < 8; c++) {
            #pragma unroll
            for (int kx = 0; kx < K1; kx++) {
                const float wv = Wb[c * 121 + ky * 11 + kx];  // uniform -> s_load
                #pragma unroll
                for (int p = 0; p < 4; p++) {
                    accP[c][p] = fmaf(a0[kx + p], wv, accP[c][p]);
                    accN[c][p] = fmaf(a1[kx + p], wv, accN[c][p]);
                }
            }
        }
    }

    const int gy  = ty0 + py;
    const int gxb = tx0 + px0;

    float vm[4];
    #pragma unroll
    for (int p = 0; p < 4; p++)
        vm[p] = s0[(py + PAD1) * S1B + px0 + PAD1 + p]
              + s1[(py + PAD1) * S1B + px0 + PAD1 + p];

    float b13[4][4], b24[4][4];
    #pragma unroll
    for (int o = 0; o < 4; o++) {
        #pragma unroll
        for (int p = 0; p < 4; p++) {
            float pe = (accP[2 * o    ][p] >= 1.f) ? 1.f : 0.f;
            float po = (accP[2 * o + 1][p] >= 1.f) ? 1.f : 0.f;
            float ne = (accN[2 * o    ][p] >= 1.f) ? 1.f : 0.f;
            float no = (accN[2 * o + 1][p] >= 1.f) ? 1.f : 0.f;
            float sa = (vm[p] * (pe - 1.5f * no) >= 1.f) ? 1.f : 0.f;
            float sb = (vm[p] * (ne - 1.5f * po) >= 1.f) ? 1.f : 0.f;
            b13[o][p] = sa + sb;
            float sc = (vm[p] * (po - 1.5f * ne) >= 1.f) ? 1.f : 0.f;
            float sd = (vm[p] * (no - 1.5f * pe) >= 1.f) ? 1.f : 0.f;
            b24[o][p] = sc + sd;
        }
    }
    float mxp[4];
    #pragma unroll
    for (int p = 0; p < 4; p++) {
        float m = 0.f;
        #pragma unroll
        for (int o = 0; o < 4; o++) m = fmaxf(m, fabsf(b13[o][p] - b24[o][p]));
        mxp[p] = m;
    }
    #pragma unroll
    for (int o = 0; o < 4; o++) {
        unsigned w0 = 0, w1 = 0, w2 = 0, w3 = 0;
        #pragma unroll
        for (int p = 0; p < 4; p++) {
            float d   = b13[o][p] - b24[o][p];
            float wta = (fabsf(d) == mxp[p]) ? 1.f : 0.f;
            float b1p = (wta * d >= 1.f)    ? 1.f : 0.f;
            float b1n = (-(wta * d) >= 1.f) ? 1.f : 0.f;
            w0 |= (unsigned)(unsigned char)(b1p * b13[o][p]) << (8 * p);
            w1 |= (unsigned)(unsigned char)(b1p * b24[o][p]) << (8 * p);
            w2 |= (unsigned)(unsigned char)(b1n * b24[o][p]) << (8 * p);
            w3 |= (unsigned)(unsigned char)(b1n * b13[o][p]) << (8 * p);
        }
        size_t base = (((size_t)b * 16 + 4 * o) * HH + gy) * WW + gxb;   // gxb % 4 == 0
        *(unsigned*)&border[base]                       = w0;
        *(unsigned*)&border[base + (size_t)HH * WW]     = w1;
        *(unsigned*)&border[base + (size_t)2 * HH * WW] = w2;
        *(unsigned*)&border[base + (size_t)3 * HH * WW] = w3;
    }
}

// ---------------- Stage 2: depthwise 23x23 conv, u8 LDS tile ----------------
// Round-20: v_pk_fma_f32 — pair accumulators over the dy dimension
// (acc2[d2][p] = {acc[2d2][p], acc[2d2+1][p]}), weight pairs pre-packed
// adjacent in memory (Wg3[c][t][kx][d]) so they land in consecutive SGPRs
// (64-bit SGPR-pair VOP3P operand); the data value c[p+kx] broadcasts to
// both halves via op_sel (free). Zero-padded weights (t-d outside [0,23))
// make all 30 rows ONE uniform guard-free loop; fma(c,+0,acc)==acc exactly,
// so results stay bit-identical. Halves the dominant FMA issue count.
#define K2 23
#define PAD2 11
#define T2X 32
#define T2Y 512
#define SROW 18        // LDS row stride in dwords (72 B); even -> b64-aligned reads
#define R2 534         // staged rows: -11 .. 522

__device__ __forceinline__ float ubyte_f(unsigned dw, int byi) {
    return (float)((dw >> (8 * byi)) & 0xffu);   // -> v_cvt_f32_ubyteN
}

// issue one staged row's 4x ds_read_b64 (8 dwords, 30 px window at lx)
__device__ __forceinline__ void s2_load(const unsigned* __restrict__ tile,
                                        int trow, int lx, unsigned d[8])
{
    const uint2* tp2 = (const uint2*)&tile[trow * SROW + 2 * lx];
    #pragma unroll
    for (int r2 = 0; r2 < 4; r2++) {
        uint2 v = tp2[r2];
        d[2 * r2] = v.x; d[2 * r2 + 1] = v.y;
    }
}

__global__ __launch_bounds__(256, 4) void stage2_kernel(
    const unsigned char* __restrict__ border, const float* __restrict__ Wg3,
    unsigned char* __restrict__ gsp)
{
    __shared__ unsigned tile[R2 * SROW];   // u8 tile, 38.4 KB

    const int z   = blockIdx.z;
    const int b   = z >> 4;
    const int c   = z & 15;
    const int tx0 = blockIdx.x * T2X;
    const unsigned char* bp = border + ((size_t)b * 16 + c) * (HH * WW);

    // ---- stage u8 rows [-11, 523), cols [tx0-12, tx0+52) as dwords ----
    for (int i = threadIdx.x; i < R2 * 16; i += 256) {
        int iy = i >> 4, cc = i & 15;
        int gy  = iy - PAD2;
        int gx0 = tx0 - 12 + 4 * cc;       // 4-aligned; in range iff 0<=gx0<=508
        unsigned u = 0;
        if (((unsigned)gy < HH) & ((unsigned)gx0 < WW))
            u = *(const unsigned*)(bp + (size_t)gy * WW + gx0);
        tile[iy * SROW + cc] = u;
    }
    __syncthreads();

    const int lx = threadIdx.x & 3;    // 4 x-groups of 8 px -> 32 wide
    const int ly = threadIdx.x >> 2;   // 64 y-groups of 8 rows -> 512 tall
    const int px = lx * 8;
    const int py = ly * 8;

    v2f acc2[4][8];                    // pair = output rows (2*d2, 2*d2+1)
    #pragma unroll
    for (int d2 = 0; d2 < 4; d2++)
        #pragma unroll
        for (int p = 0; p < 8; p++) acc2[d2][p] = (v2f){0.f, 0.f};

    const float* wc3 = Wg3 + (size_t)c * (30 * 184);

    unsigned dc[8];
    s2_load(tile, py + 0, lx, dc);         // prologue: row t=0

    // ---- ONE uniform loop over all 30 staged rows (weights zero-padded) ----
    #pragma unroll 1
    for (int t = 0; t < 30; t++) {
        float cv[30];                      // cv[i] = pixel byte (i+1) of window
        #pragma unroll
        for (int j = 0; j < 30; j++) cv[j] = ubyte_f(dc[(j + 1) >> 2], (j + 1) & 3);
        if (t < 29) s2_load(tile, py + t + 1, lx, dc);   // uniform branch

        const v2f* wt = (const v2f*)(wc3 + t * 184);     // 92 sgpr pairs this row
        #pragma unroll
        for (int kx = 0; kx < K2; kx++) {
            #pragma unroll
            for (int p = 0; p < 8; p++) {
                const float cs = cv[p + kx];             // static idx <= 29
                const v2f cb = {cs, cs};                 // op_sel broadcast
                #pragma unroll
                for (int d2 = 0; d2 < 4; d2++)
                    acc2[d2][p] = __builtin_elementwise_fma(cb, wt[kx * 4 + d2],
                                                            acc2[d2][p]);
            }
        }
    }

    // ---- spike + write u8 plane ----
    const int ox = tx0 + px;               // multiple of 8 -> uint2 store OK
    unsigned char* gp = gsp + ((size_t)b * 16 + c) * (HH * WW);
    #pragma unroll
    for (int dy = 0; dy < 8; dy++) {
        const int oy = py + dy;
        unsigned lo = 0, hi = 0;
        #pragma unroll
        for (int p = 0; p < 4; p++) {
            float av = (dy & 1) ? acc2[dy >> 1][p].y : acc2[dy >> 1][p].x;
            lo |= (av >= 1.f ? 1u : 0u) << (8 * p);
        }
        #pragma unroll
        for (int p = 0; p < 4; p++) {
            float av = (dy & 1) ? acc2[dy >> 1][p + 4].y : acc2[dy >> 1][p + 4].x;
            hi |= (av >= 1.f ? 1u : 0u) << (8 * p);
        }
        uint2 v; v.x = lo; v.y = hi;
        *(uint2*)&gp[(size_t)oy * WW + ox] = v;
    }
}

// ---------------- Stage 3: combine 16 spike planes -> output ----------------
__global__ __launch_bounds__(256) void combine_kernel(
    const unsigned char* __restrict__ gsp, float* __restrict__ out)
{
    const int idx = blockIdx.x * 256 + threadIdx.x;   // uint granules
    const int b = idx >> 16;
    const int r = idx & 65535;
    const unsigned* g = (const unsigned*)gsp;
    const int pb = b * 16;
    unsigned s = 0;
    #pragma unroll
    for (int o = 0; o < 4; o++) {
        unsigned g0 = g[(size_t)(pb + 4 * o + 0) * 65536 + r];
        unsigned g1 = g[(size_t)(pb + 4 * o + 1) * 65536 + r];
        unsigned g2 = g[(size_t)(pb + 4 * o + 2) * 65536 + r];
        unsigned g3 = g[(size_t)(pb + 4 * o + 3) * 65536 + r];
        s += ((g0 & ~g1) & 0x01010101u) + ((g2 & ~g3) & 0x01010101u);
    }
    float4 f;
    f.x = (float)(s & 255u);
    f.y = (float)((s >> 8) & 255u);
    f.z = (float)((s >> 16) & 255u);
    f.w = (float)(s >> 24);
    ((float4*)out)[idx] = f;
}

extern "C" void kernel_launch(void* const* d_in, const int* in_sizes, int n_in,
                              void* d_out, int out_size, void* d_ws, size_t ws_size,
                              hipStream_t stream)
{
    const float* inp = (const float*)d_in[0];   // (4,2,512,512) f32
    const float* Wb  = (const float*)d_in[1];   // (8,1,11,11)   f32
    const float* Wg  = (const float*)d_in[2];   // (16,1,23,23)  f32
    unsigned char* border = (unsigned char*)d_ws;                       // 16.78 MB
    unsigned char* gsp    = border + (size_t)NB * 16 * HH * WW;         // +16.78 MB
    float* out = (float*)d_out;                 // (4,512,512)   f32

    // packed stage2 weights in d_out tail (353 KB at +2 MB; combine_kernel
    // fully overwrites d_out afterwards -> safe scratch, proven in r6).
    float* Wg3 = (float*)((char*)d_out + (2u << 20));

    dim3 blk(256);
    prep_kernel<<<dim3((WG3_ELEMS + 255) / 256), blk, 0, stream>>>(Wg, Wg3);
    dim3 g1(WW / T1X, HH / T1Y, NB);        // 16x16x4 = 1024 blocks
    stage1_kernel<<<g1, blk, 0, stream>>>(inp, Wb, border);
    dim3 g2(WW / T2X, 1, NB * 16);          // 16x1x64 = 1024 blocks, 4/CU resident
    stage2_kernel<<<g2, blk, 0, stream>>>(border, Wg3, gsp);
    dim3 g3((NB * HH * WW / 4) / 256);      // 1024 blocks
    combine_kernel<<<g3, blk, 0, stream>>>(gsp, out);
}

// Round 12
// 277.084 us; speedup vs baseline: 1.1081x; 1.1081x over previous
//
#include <hip/hip_runtime.h>

#define HH 512
#define WW 512
#define NB 4

typedef float v2f __attribute__((ext_vector_type(2)));

// ---------------- Stage 1: 11x11 convs (1->8, pos & neg) + spike/WTA logic ----------------
// Round-19 version (fused pos+neg, 4 px/thread) — proven, unchanged.
#define K1 11
#define PAD1 5
#define T1X 32
#define T1Y 32
#define IN1 42        // 32 + 10 halo
#define S1B 44        // LDS row stride (even -> b64-aligned float2 reads)

__global__ __launch_bounds__(256, 4) void stage1_kernel(
    const float* __restrict__ inp, const float* __restrict__ Wb,
    unsigned char* __restrict__ border)
{
    __shared__ __align__(16) float s0[IN1 * S1B];
    __shared__ __align__(16) float s1[IN1 * S1B];

    const int b   = blockIdx.z;
    const int tx0 = blockIdx.x * T1X;
    const int ty0 = blockIdx.y * T1Y;
    const float* in0 = inp + ((size_t)b * 2 + 0) * (HH * WW);
    const float* in1 = inp + ((size_t)b * 2 + 1) * (HH * WW);

    for (int i = threadIdx.x; i < IN1 * IN1; i += 256) {
        int iy = i / IN1, ix = i - iy * IN1;
        int gy = ty0 + iy - PAD1, gx = tx0 + ix - PAD1;
        bool ok = (gy >= 0) & (gy < HH) & (gx >= 0) & (gx < WW);
        int idx = gy * WW + gx;
        s0[iy * S1B + ix] = ok ? in0[idx] : 0.f;
        s1[iy * S1B + ix] = ok ? in1[idx] : 0.f;
    }
    __syncthreads();

    const int lx  = threadIdx.x & 7;    // 8 x-groups of 4 px -> 32 wide
    const int ly  = threadIdx.x >> 3;   // 32 rows
    const int px0 = lx * 4;
    const int py  = ly;

    float accP[8][4], accN[8][4];
    #pragma unroll
    for (int c = 0; c < 8; c++)
        #pragma unroll
        for (int p = 0; p < 4; p++) { accP[c][p] = 0.f; accN[c][p] = 0.f; }

    #pragma unroll 1
    for (int ky = 0; ky < K1; ky++) {
        float a0[14], a1[14];
        const float2* r0 = (const float2*)&s0[(py + ky) * S1B + px0];
        const float2* r1 = (const float2*)&s1[(py + ky) * S1B + px0];
        #pragma unroll
        for (int r = 0; r < 7; r++) {
            *(float2*)&a0[2 * r] = r0[r];
            *(float2*)&a1[2 * r] = r1[r];
        }
        #pragma unroll
        for (int c = 0; c < 8; c++) {
            #pragma unroll
            for (int kx = 0; kx < K1; kx++) {
                const float wv = Wb[c * 121 + ky * 11 + kx];  // uniform -> s_load
                #pragma unroll
                for (int p = 0; p < 4; p++) {
                    accP[c][p] = fmaf(a0[kx + p], wv, accP[c][p]);
                    accN[c][p] = fmaf(a1[kx + p], wv, accN[c][p]);
                }
            }
        }
    }

    const int gy  = ty0 + py;
    const int gxb = tx0 + px0;

    float vm[4];
    #pragma unroll
    for (int p = 0; p < 4; p++)
        vm[p] = s0[(py + PAD1) * S1B + px0 + PAD1 + p]
              + s1[(py + PAD1) * S1B + px0 + PAD1 + p];

    float b13[4][4], b24[4][4];
    #pragma unroll
    for (int o = 0; o < 4; o++) {
        #pragma unroll
        for (int p = 0; p < 4; p++) {
            float pe = (accP[2 * o    ][p] >= 1.f) ? 1.f : 0.f;
            float po = (accP[2 * o + 1][p] >= 1.f) ? 1.f : 0.f;
            float ne = (accN[2 * o    ][p] >= 1.f) ? 1.f : 0.f;
            float no = (accN[2 * o + 1][p] >= 1.f) ? 1.f : 0.f;
            float sa = (vm[p] * (pe - 1.5f * no) >= 1.f) ? 1.f : 0.f;
            float sb = (vm[p] * (ne - 1.5f * po) >= 1.f) ? 1.f : 0.f;
            b13[o][p] = sa + sb;
            float sc = (vm[p] * (po - 1.5f * ne) >= 1.f) ? 1.f : 0.f;
            float sd = (vm[p] * (no - 1.5f * pe) >= 1.f) ? 1.f : 0.f;
            b24[o][p] = sc + sd;
        }
    }
    float mxp[4];
    #pragma unroll
    for (int p = 0; p < 4; p++) {
        float m = 0.f;
        #pragma unroll
        for (int o = 0; o < 4; o++) m = fmaxf(m, fabsf(b13[o][p] - b24[o][p]));
        mxp[p] = m;
    }
    #pragma unroll
    for (int o = 0; o < 4; o++) {
        unsigned w0 = 0, w1 = 0, w2 = 0, w3 = 0;
        #pragma unroll
        for (int p = 0; p < 4; p++) {
            float d   = b13[o][p] - b24[o][p];
            float wta = (fabsf(d) == mxp[p]) ? 1.f : 0.f;
            float b1p = (wta * d >= 1.f)    ? 1.f : 0.f;
            float b1n = (-(wta * d) >= 1.f) ? 1.f : 0.f;
            w0 |= (unsigned)(unsigned char)(b1p * b13[o][p]) << (8 * p);
            w1 |= (unsigned)(unsigned char)(b1p * b24[o][p]) << (8 * p);
            w2 |= (unsigned)(unsigned char)(b1n * b24[o][p]) << (8 * p);
            w3 |= (unsigned)(unsigned char)(b1n * b13[o][p]) << (8 * p);
        }
        size_t base = (((size_t)b * 16 + 4 * o) * HH + gy) * WW + gxb;   // gxb % 4 == 0
        *(unsigned*)&border[base]                       = w0;
        *(unsigned*)&border[base + (size_t)HH * WW]     = w1;
        *(unsigned*)&border[base + (size_t)2 * HH * WW] = w2;
        *(unsigned*)&border[base + (size_t)3 * HH * WW] = w3;
    }
}

// ---------------- Stage 2: depthwise 23x23 conv, u8 LDS tile ----------------
// Round-22: v_pk_fma_f32 paired over PX (not dy — r10/r11's dy pairing needed
// 92 weight pairs in SGPRs -> per-lane VGPR weights -> memory spill, refuted).
// Weight = single scalar s_load broadcast to both halves (one SGPR read +
// op_sel: VOP3P-legal). Data pair = even-aligned VGPR pair from dual decoded
// windows: aO[o]={byte 2o+1,2o+2} (even kx), aE[e]={byte 2e,2e+1} (odd kx).
// Output pair (px 2i, 2i+1) at kx needs bytes {2i+kx+1, 2i+kx+2}:
//   kx=2m   -> aO[i+m];  kx=2m+1 -> aE[i+m+1].   All indices static.
// 4 output rows/thread (r3 geometry) keeps regs ~108 < 128 cap.
#define K2 23
#define PAD2 11
#define T2X 32
#define T2Y 256
#define SROW 18        // LDS row stride in dwords (72 B)
#define R2 278         // staged rows: ty0-11 .. ty0+266

__device__ __forceinline__ float ubyte_f(unsigned dw, int byi) {
    return (float)((dw >> (8 * byi)) & 0xffu);   // -> v_cvt_f32_ubyteN
}

// issue one staged row's 4x ds_read_b64 (8 dwords = bytes 0..31)
__device__ __forceinline__ void s2_load(const unsigned* __restrict__ tile,
                                        int trow, int lx, unsigned d[8])
{
    const uint2* tp2 = (const uint2*)&tile[trow * SROW + 2 * lx];
    #pragma unroll
    for (int r2 = 0; r2 < 4; r2++) {
        uint2 v = tp2[r2];
        d[2 * r2] = v.x; d[2 * r2 + 1] = v.y;
    }
}

__global__ __launch_bounds__(256, 4) void stage2_kernel(
    const unsigned char* __restrict__ border, const float* __restrict__ Wg,
    unsigned char* __restrict__ gsp)
{
    __shared__ unsigned tile[R2 * SROW];   // u8 tile, 20.0 KB

    const int z   = blockIdx.z;
    const int b   = z >> 4;
    const int c   = z & 15;
    const int tx0 = blockIdx.x * T2X;
    const int ty0 = blockIdx.y * T2Y;
    const unsigned char* bp = border + ((size_t)b * 16 + c) * (HH * WW);

    // ---- stage u8 rows [ty0-11, ty0+267), cols [tx0-12, tx0+52) as dwords ----
    for (int i = threadIdx.x; i < R2 * 16; i += 256) {
        int iy = i >> 4, cc = i & 15;
        int gy  = ty0 - PAD2 + iy;
        int gx0 = tx0 - 12 + 4 * cc;       // 4-aligned; in range iff 0<=gx0<=508
        unsigned u = 0;
        if (((unsigned)gy < HH) & ((unsigned)gx0 < WW))
            u = *(const unsigned*)(bp + (size_t)gy * WW + gx0);
        tile[iy * SROW + cc] = u;
    }
    __syncthreads();

    const int lx = threadIdx.x & 3;    // 4 x-groups of 8 px -> 32 wide
    const int ly = threadIdx.x >> 2;   // 64 y-groups of 4 rows -> 256 tall
    const int px = lx * 8;
    const int py = ly * 4;

    v2f acc2[4][4];                    // [dy][pair i] ; .x = px 2i, .y = px 2i+1
    #pragma unroll
    for (int dy = 0; dy < 4; dy++)
        #pragma unroll
        for (int i = 0; i < 4; i++) acc2[dy][i] = (v2f){0.f, 0.f};

    const float* wc = Wg + c * (K2 * K2);

    unsigned dc[8];
    s2_load(tile, py + 0, lx, dc);         // prologue: row t=0

    // ---- rolling rows t=0..25; dy FULLY unrolled, static acc, uniform guards ----
    #pragma unroll 1
    for (int t = 0; t < 26; t++) {
        v2f aE[15], aO[15];                // dual byte-pair decode of window
        #pragma unroll
        for (int e = 0; e < 15; e++)
            aE[e] = (v2f){ubyte_f(dc[(2*e)   >> 2], (2*e)   & 3),
                          ubyte_f(dc[(2*e+1) >> 2], (2*e+1) & 3)};
        #pragma unroll
        for (int o = 0; o < 15; o++)
            aO[o] = (v2f){ubyte_f(dc[(2*o+1) >> 2], (2*o+1) & 3),
                          ubyte_f(dc[(2*o+2) >> 2], (2*o+2) & 3)};
        if (t < 25) s2_load(tile, py + t + 1, lx, dc);   // trow <= 277 < R2

        #pragma unroll
        for (int dy = 0; dy < 4; dy++) {
            const int ky = t - dy;                // runtime-uniform
            if (ky >= 0 && ky < K2) {
                const float* wr = wc + ky * K2;
                #pragma unroll
                for (int kx = 0; kx < K2; kx++) {
                    const float wv = wr[kx];      // uniform -> s_load scalar
                    const v2f wb = (v2f){wv, wv}; // op_sel broadcast
                    #pragma unroll
                    for (int i = 0; i < 4; i++) {
                        const v2f op = (kx & 1) ? aE[i + (kx + 1) / 2]
                                                : aO[i + kx / 2];
                        acc2[dy][i] = __builtin_elementwise_fma(op, wb, acc2[dy][i]);
                    }
                }
            }
        }
    }

    // ---- spike + write u8 plane ----
    const int ox = tx0 + px;               // multiple of 8 -> uint2 store OK
    unsigned char* gp = gsp + ((size_t)b * 16 + c) * (HH * WW);
    #pragma unroll
    for (int dy = 0; dy < 4; dy++) {
        const int oy = ty0 + py + dy;
        unsigned lo = 0, hi = 0;
        #pragma unroll
        for (int i = 0; i < 2; i++) {
            lo |= (acc2[dy][i].x >= 1.f ? 1u : 0u) << (16 * i);
            lo |= (acc2[dy][i].y >= 1.f ? 1u : 0u) << (16 * i + 8);
        }
        #pragma unroll
        for (int i = 0; i < 2; i++) {
            hi |= (acc2[dy][i + 2].x >= 1.f ? 1u : 0u) << (16 * i);
            hi |= (acc2[dy][i + 2].y >= 1.f ? 1u : 0u) << (16 * i + 8);
        }
        uint2 v; v.x = lo; v.y = hi;
        *(uint2*)&gp[(size_t)oy * WW + ox] = v;
    }
}

// ---------------- Stage 3: combine 16 spike planes -> output ----------------
__global__ __launch_bounds__(256) void combine_kernel(
    const unsigned char* __restrict__ gsp, float* __restrict__ out)
{
    const int idx = blockIdx.x * 256 + threadIdx.x;   // uint granules
    const int b = idx >> 16;
    const int r = idx & 65535;
    const unsigned* g = (const unsigned*)gsp;
    const int pb = b * 16;
    unsigned s = 0;
    #pragma unroll
    for (int o = 0; o < 4; o++) {
        unsigned g0 = g[(size_t)(pb + 4 * o + 0) * 65536 + r];
        unsigned g1 = g[(size_t)(pb + 4 * o + 1) * 65536 + r];
        unsigned g2 = g[(size_t)(pb + 4 * o + 2) * 65536 + r];
        unsigned g3 = g[(size_t)(pb + 4 * o + 3) * 65536 + r];
        s += ((g0 & ~g1) & 0x01010101u) + ((g2 & ~g3) & 0x01010101u);
    }
    float4 f;
    f.x = (float)(s & 255u);
    f.y = (float)((s >> 8) & 255u);
    f.z = (float)((s >> 16) & 255u);
    f.w = (float)(s >> 24);
    ((float4*)out)[idx] = f;
}

extern "C" void kernel_launch(void* const* d_in, const int* in_sizes, int n_in,
                              void* d_out, int out_size, void* d_ws, size_t ws_size,
                              hipStream_t stream)
{
    const float* inp = (const float*)d_in[0];   // (4,2,512,512) f32
    const float* Wb  = (const float*)d_in[1];   // (8,1,11,11)   f32
    const float* Wg  = (const float*)d_in[2];   // (16,1,23,23)  f32
    unsigned char* border = (unsigned char*)d_ws;                       // 16.78 MB
    unsigned char* gsp    = border + (size_t)NB * 16 * HH * WW;         // +16.78 MB
    float* out = (float*)d_out;                 // (4,512,512)   f32

    dim3 blk(256);
    dim3 g1(WW / T1X, HH / T1Y, NB);        // 16x16x4 = 1024 blocks
    stage1_kernel<<<g1, blk, 0, stream>>>(inp, Wb, border);
    dim3 g2(WW / T2X, HH / T2Y, NB * 16);   // 16x2x64 = 2048 blocks
    stage2_kernel<<<g2, blk, 0, stream>>>(border, Wg, gsp);
    dim3 g3((NB * HH * WW / 4) / 256);      // 1024 blocks
    combine_kernel<<<g3, blk, 0, stream>>>(gsp, out);
}